// Round 1
// baseline (748.150 us; speedup 1.0000x reference)
//
#include <hip/hip_runtime.h>
#include <hip/hip_bf16.h>

// Shapes: N=4, C=128, H=W=256, CC=64. x_down: 64x64. phi/g spatial: 32x32.
// Q = 4096 (64x64), V = 1024 (32x32).

// ---------------------------------------------------------------- utilities
__device__ __forceinline__ float wredMax(float v) {
#pragma unroll
  for (int mask = 32; mask >= 1; mask >>= 1) v = fmaxf(v, __shfl_xor(v, mask, 64));
  return v;
}
__device__ __forceinline__ float wredSum(float v) {
#pragma unroll
  for (int mask = 32; mask >= 1; mask >>= 1) v += __shfl_xor(v, mask, 64);
  return v;
}

// ------------------------------------------------ 1. depthwise 4x4 stride-4
// x [n][128][256][256] * dw [128][4][4] -> xd [n][128][64][64]
__global__ __launch_bounds__(256) void k_down(const float* __restrict__ x,
                                              const float* __restrict__ dw,
                                              float* __restrict__ xd) {
  const int n = blockIdx.z, c = blockIdx.y;
  const int p = blockIdx.x * 256 + threadIdx.x;  // 0..4095
  const int i = p >> 6, j = p & 63;
  const float* xp = x + (((size_t)(n * 128 + c) * 256) + i * 4) * 256 + j * 4;
  const float* wp = dw + c * 16;
  float acc = 0.f;
#pragma unroll
  for (int a = 0; a < 4; ++a) {
    float4 v = *(const float4*)(xp + a * 256);
    acc += v.x * wp[a * 4 + 0] + v.y * wp[a * 4 + 1] + v.z * wp[a * 4 + 2] + v.w * wp[a * 4 + 3];
  }
  xd[(size_t)(n * 128 + c) * 4096 + p] = acc;
}

// ------------------------------------- 2. conv1x1, channel-major, 4 outputs
// in [n][Cin][P], w [O][Cin], b [O] -> out [n][O][P]
__global__ __launch_bounds__(256) void k_conv_cm4(const float* __restrict__ in,
                                                  const float* __restrict__ w,
                                                  const float* __restrict__ b,
                                                  float* __restrict__ out,
                                                  int Cin, int P, int O) {
  const int n = blockIdx.z, o4 = blockIdx.y * 4;
  const int p = blockIdx.x * 256 + threadIdx.x;
  const float* ip = in + (size_t)n * Cin * P + p;
  float a0 = b[o4], a1 = b[o4 + 1], a2 = b[o4 + 2], a3 = b[o4 + 3];
  const float* w0 = w + (size_t)o4 * Cin;
  const float* w1 = w0 + Cin;
  const float* w2 = w1 + Cin;
  const float* w3 = w2 + Cin;
  for (int c = 0; c < Cin; ++c) {
    const float v = ip[(size_t)c * P];
    a0 += v * w0[c]; a1 += v * w1[c]; a2 += v * w2[c]; a3 += v * w3[c];
  }
  size_t ob = ((size_t)n * O + o4) * P + p;
  out[ob] = a0; out[ob + P] = a1; out[ob + 2 * (size_t)P] = a2; out[ob + 3 * (size_t)P] = a3;
}

// ------------------------------------------------------------- 3. maxpool2
__global__ __launch_bounds__(256) void k_maxpool2(const float* __restrict__ in,
                                                  float* __restrict__ out,
                                                  int H, int W) {
  const int n = blockIdx.z, c = blockIdx.y;
  const int oh = H / 2, ow = W / 2;
  const int p = blockIdx.x * 256 + threadIdx.x;
  if (p >= oh * ow) return;
  const int i = p / ow, j = p % ow;
  const float* ip = in + ((size_t)(n * 64 + c) * H + 2 * i) * W + 2 * j;
  float m = fmaxf(fmaxf(ip[0], ip[1]), fmaxf(ip[W], ip[W + 1]));
  out[((size_t)(n * 64 + c) * oh + i) * ow + j] = m;
}

// -------------------------------------- 4. pyramid avg-pools (8,4,2,1 grid)
// in [n][64][H][H] -> pooled [n][64][85] (64 + 16 + 4 + 1, row-major cells)
__global__ __launch_bounds__(256) void k_pool(const float* __restrict__ in,
                                              float* __restrict__ pooled, int H) {
  __shared__ float red[64][4];
  __shared__ float s8[64];
  const int blk = blockIdx.x;
  const int n = blk >> 6, c = blk & 63;
  const int t = threadIdx.x;
  const int cell = t & 63, part = t >> 6;
  const int gy = cell >> 3, gx = cell & 7;
  const int k = H >> 3;            // 8 or 4
  const int rpp = (k >> 2) ? (k >> 2) : 1;  // rows per part: 2 or 1
  const float* base = in + (size_t)(n * 64 + c) * H * H;
  float s = 0.f;
  for (int r = 0; r < rpp; ++r) {
    const int y = gy * k + part * rpp + r;
    const float* rp = base + y * H + gx * k;
    for (int xx = 0; xx < k; xx += 4) {
      float4 v = *(const float4*)(rp + xx);
      s += v.x + v.y + v.z + v.w;
    }
  }
  red[cell][part] = s;
  __syncthreads();
  if (t < 64) s8[t] = red[t][0] + red[t][1] + red[t][2] + red[t][3];
  __syncthreads();
  float* pout = pooled + (size_t)(n * 64 + c) * 85;
  const float inv = 1.f / (float)(k * k);
  if (t < 64) {
    pout[t] = s8[t] * inv;
  } else if (t < 80) {
    const int i2 = t - 64, gy2 = i2 >> 2, gx2 = i2 & 3;
    float v = s8[(2 * gy2) * 8 + 2 * gx2] + s8[(2 * gy2) * 8 + 2 * gx2 + 1] +
              s8[(2 * gy2 + 1) * 8 + 2 * gx2] + s8[(2 * gy2 + 1) * 8 + 2 * gx2 + 1];
    pout[64 + i2] = v * inv * 0.25f;
  } else if (t < 84) {
    const int i1 = t - 80, gy1 = i1 >> 1, gx1 = i1 & 1;
    float v = 0.f;
    for (int yy = 0; yy < 4; ++yy)
      for (int xx = 0; xx < 4; ++xx) v += s8[(gy1 * 4 + yy) * 8 + gx1 * 4 + xx];
    pout[80 + i1] = v * inv * 0.0625f;
  } else if (t == 84) {
    float v = 0.f;
    for (int i = 0; i < 64; ++i) v += s8[i];
    pout[84] = v * inv * (1.f / 64.f);
  }
}

// -------------------- 5. pyramid level conv (64->16) + BN(eval) + ReLU
// pooled [n][64][85], pw [4][16][64] -> q [n][85][16]
__global__ __launch_bounds__(256) void k_poolconv(const float* __restrict__ pooled,
                                                  const float* __restrict__ pw,
                                                  const float* __restrict__ gamma,
                                                  const float* __restrict__ beta,
                                                  float* __restrict__ qout) {
  const int n = blockIdx.x;
  const float bnscale = 0.9999950000374997f;  // 1/sqrt(1+1e-5)
  for (int idx = threadIdx.x; idx < 85 * 16; idx += 256) {
    const int pos = idx >> 4, o = idx & 15;
    const int s = (pos < 64) ? 0 : (pos < 80) ? 1 : (pos < 84) ? 2 : 3;
    const float* pp = pooled + (size_t)n * 64 * 85 + pos;
    const float* wp = pw + (s * 16 + o) * 64;
    float acc = 0.f;
    for (int c = 0; c < 64; ++c) acc += pp[c * 85] * wp[c];
    acc = acc * bnscale * gamma[s * 16 + o] + beta[s * 16 + o];
    qout[((size_t)n * 85 + pos) * 16 + o] = fmaxf(acc, 0.f);
  }
}

// --------- 6. pyramid fuse: bilinear-up(4 scales) + concat + conv128->64
// in [n][64][S*S] ch-major, q [n][85][16], ow [64][128], ob [64]
// out: pos_major ? [n][S*S][64] : [n][64][S*S]
__global__ __launch_bounds__(256) void k_ppfuse(const float* __restrict__ in,
                                                const float* __restrict__ q,
                                                const float* __restrict__ ow,
                                                const float* __restrict__ ob,
                                                float* __restrict__ out,
                                                int S, int lw, int pos_major) {
  __shared__ float bl[64][65];   // blended pyramid features [pixel][64]
  __shared__ float til[64][65];  // identity tile [pixel][64]; reused for output staging
  const int n = blockIdx.y;
  const int P = S * S;
  const int pixbase = blockIdx.x * 64;
  const int t = threadIdx.x;
  const int p = t & 63, sc = t >> 6;

  // phase 1: per-pixel bilinear blend of scale `sc` (16 channels)
  {
    const int pg = pixbase + p;
    const int y = pg >> lw, x = pg & (S - 1);
    const int ps = 8 >> sc;
    const int off = (sc == 0) ? 0 : (sc == 1) ? 64 : (sc == 2) ? 80 : 84;
    const float scale = (float)ps / (float)S;
    float syf = fminf(fmaxf((y + 0.5f) * scale - 0.5f, 0.f), (float)(ps - 1));
    float sxf = fminf(fmaxf((x + 0.5f) * scale - 0.5f, 0.f), (float)(ps - 1));
    const int ly = (int)syf, lx = (int)sxf;
    const int hy = min(ly + 1, ps - 1), hx = min(lx + 1, ps - 1);
    const float fy = syf - ly, fx = sxf - lx;
    const float w00 = (1.f - fy) * (1.f - fx), w01 = (1.f - fy) * fx;
    const float w10 = fy * (1.f - fx), w11 = fy * fx;
    const float* qn = q + (size_t)n * 85 * 16;
    const float4* r00 = (const float4*)(qn + (off + ly * ps + lx) * 16);
    const float4* r01 = (const float4*)(qn + (off + ly * ps + hx) * 16);
    const float4* r10 = (const float4*)(qn + (off + hy * ps + lx) * 16);
    const float4* r11 = (const float4*)(qn + (off + hy * ps + hx) * 16);
#pragma unroll
    for (int k = 0; k < 4; ++k) {
      float4 v00 = r00[k], v01 = r01[k], v10 = r10[k], v11 = r11[k];
      bl[p][sc * 16 + 4 * k + 0] = w00 * v00.x + w01 * v01.x + w10 * v10.x + w11 * v11.x;
      bl[p][sc * 16 + 4 * k + 1] = w00 * v00.y + w01 * v01.y + w10 * v10.y + w11 * v11.y;
      bl[p][sc * 16 + 4 * k + 2] = w00 * v00.z + w01 * v01.z + w10 * v10.z + w11 * v11.z;
      bl[p][sc * 16 + 4 * k + 3] = w00 * v00.w + w01 * v01.w + w10 * v10.w + w11 * v11.w;
    }
  }
  // phase 2: load identity tile (transposed into [pixel][c])
  {
    const float* ip = in + (size_t)n * 64 * P + pixbase + p;
#pragma unroll
    for (int k = 0; k < 16; ++k) {
      const int c = sc + 4 * k;
      til[p][c] = ip[(size_t)c * P];
    }
  }
  __syncthreads();
  // phase 3: 128->64 conv; thread handles pixel p, 16 outputs (obase..obase+15)
  const int obase = sc * 16;
  float acc[16];
#pragma unroll
  for (int j = 0; j < 16; ++j) acc[j] = ob[obase + j];
  const float4* ow4 = (const float4*)ow;
#pragma unroll
  for (int c4 = 0; c4 < 16; ++c4) {
    const float4 tv = make_float4(til[p][4 * c4], til[p][4 * c4 + 1], til[p][4 * c4 + 2], til[p][4 * c4 + 3]);
    const float4 bv = make_float4(bl[p][4 * c4], bl[p][4 * c4 + 1], bl[p][4 * c4 + 2], bl[p][4 * c4 + 3]);
#pragma unroll
    for (int j = 0; j < 16; ++j) {
      const float4 wv = ow4[(obase + j) * 32 + c4];
      const float4 wb = ow4[(obase + j) * 32 + 16 + c4];
      acc[j] += tv.x * wv.x + tv.y * wv.y + tv.z * wv.z + tv.w * wv.w +
                bv.x * wb.x + bv.y * wb.y + bv.z * wb.z + bv.w * wb.w;
    }
  }
  // phase 4
  if (pos_major) {
    __syncthreads();
#pragma unroll
    for (int j = 0; j < 16; ++j) til[p][obase + j] = acc[j];
    __syncthreads();
    const int p2 = t >> 2, c2 = (t & 3) * 16;
    float4* dst4 = (float4*)(out + (size_t)n * P * 64 + (size_t)pixbase * 64 + (size_t)t * 16);
#pragma unroll
    for (int k4 = 0; k4 < 4; ++k4)
      dst4[k4] = make_float4(til[p2][c2 + 4 * k4], til[p2][c2 + 4 * k4 + 1],
                             til[p2][c2 + 4 * k4 + 2], til[p2][c2 + 4 * k4 + 3]);
  } else {
#pragma unroll
    for (int j = 0; j < 16; ++j)
      out[((size_t)n * 64 + obase + j) * P + pixbase + p] = acc[j];
  }
}

// ------------------------- 7. depth map resizes (align_corners=True), 1 ch
__global__ __launch_bounds__(256) void k_dresize(const float* __restrict__ depth,
                                                 float* __restrict__ d1,
                                                 float* __restrict__ d2) {
  const int n = blockIdx.y;
  const int bx = blockIdx.x;
  const float* dp = depth + (size_t)n * 65536;
  int i, j, idx;
  float scale;
  float* outp;
  if (bx < 16) {
    idx = bx * 256 + threadIdx.x;  // 0..4095
    i = idx >> 6; j = idx & 63;
    scale = 255.f / 63.f;
    outp = d1 + (size_t)n * 4096;
  } else {
    idx = (bx - 16) * 256 + threadIdx.x;  // 0..1023
    i = idx >> 5; j = idx & 31;
    scale = 255.f / 31.f;
    outp = d2 + (size_t)n * 1024;
  }
  const float sy = i * scale, sx = j * scale;
  const int ly = (int)sy, lx = (int)sx;
  const int hy = min(ly + 1, 255), hx = min(lx + 1, 255);
  const float fy = sy - ly, fx = sx - lx;
  const float v = (1.f - fy) * ((1.f - fx) * dp[ly * 256 + lx] + fx * dp[ly * 256 + hx]) +
                  fy * ((1.f - fx) * dp[hy * 256 + lx] + fx * dp[hy * 256 + hx]);
  outp[idx] = v;
}

// -------------------------------------------------------------- 8. attention
__device__ __forceinline__ void softmax_row(float (&ar)[16], float dq,
                                            const float* __restrict__ d2p,
                                            int l, float* Srow) {
  const float e = 1e-6f;
  const float rcp_dq = 1.f / (dq + e);
  float m = -1e30f, mr = -1e30f;
#pragma unroll
  for (int i = 0; i < 16; ++i) {
    m = fmaxf(m, ar[i]);
    const float dd = d2p[l + 64 * i];
    const float r = fminf(dq / (dd + e), dd * rcp_dq);
    mr = fmaxf(mr, r);
  }
  m = wredMax(m); mr = wredMax(mr);
  float se = 0.f, sr = 0.f;
#pragma unroll
  for (int i = 0; i < 16; ++i) {
    const float dd = d2p[l + 64 * i];
    const float r = fminf(dq / (dd + e), dd * rcp_dq);
    const float ea = __expf(ar[i] - m), er = __expf(r - mr);
    se += ea; sr += er;
    ar[i] = ea * er;  // unnormalized Ra*Rd (up to factor U)
  }
  se = wredSum(se); sr = wredSum(sr);
  const float U = 1.f / (se * sr);  // p_i = ar[i] * U, p in (0,1]
  float mu = -1e30f;
#pragma unroll
  for (int i = 0; i < 16; ++i) mu = fmaxf(mu, ar[i]);
  mu = wredMax(mu);
  float sp = 0.f;
#pragma unroll
  for (int i = 0; i < 16; ++i) {
    ar[i] = __expf(U * (ar[i] - mu));
    sp += ar[i];
  }
  sp = wredSum(sp);
  const float isp = 1.f / sp;
#pragma unroll
  for (int i = 0; i < 16; ++i) Srow[i * 64] = ar[i] * isp;
}

// thetaT [n][4096][64], phi [n][64][1024], gT [n][1024][64],
// d1 [n][4096], d2 [n][1024] -> yT [n][4096][64]
__global__ __launch_bounds__(256) void k_attn(const float* __restrict__ thetaT,
                                              const float* __restrict__ phi,
                                              const float* __restrict__ gT,
                                              const float* __restrict__ d1,
                                              const float* __restrict__ d2,
                                              float* __restrict__ yT) {
  __shared__ __align__(16) float Pbuf[16384];  // phi tile [16c][1024v] -> reused as S [16q][1024v]
  const int n = blockIdx.y, q0 = blockIdx.x * 16;
  const int t = threadIdx.x, w = t >> 6, l = t & 63;

  float a0[16], a1[16], a2[16], a3[16];
#pragma unroll
  for (int i = 0; i < 16; ++i) { a0[i] = 0.f; a1[i] = 0.f; a2[i] = 0.f; a3[i] = 0.f; }

  const float4* phisrc = (const float4*)(phi + (size_t)n * 65536);
  const float* thp = thetaT + ((size_t)n * 4096 + q0 + w * 4) * 64;  // 4 rows for this wave

  for (int ct = 0; ct < 4; ++ct) {
    __syncthreads();
#pragma unroll
    for (int k = 0; k < 16; ++k)
      ((float4*)Pbuf)[k * 256 + t] = phisrc[ct * 4096 + k * 256 + t];
    __syncthreads();
#pragma unroll
    for (int cl = 0; cl < 16; ++cl) {
      const int c = ct * 16 + cl;
      const float t0 = thp[c], t1 = thp[64 + c], t2 = thp[128 + c], t3 = thp[192 + c];
      const float* pr = Pbuf + cl * 1024 + l;
#pragma unroll
      for (int i = 0; i < 16; ++i) {
        const float pv = pr[i * 64];
        a0[i] += t0 * pv; a1[i] += t1 * pv; a2[i] += t2 * pv; a3[i] += t3 * pv;
      }
    }
  }
  __syncthreads();  // phi reads done; Pbuf becomes S

  const float* d2p = d2 + (size_t)n * 1024;
  const float* d1p = d1 + (size_t)n * 4096 + q0 + w * 4;
  softmax_row(a0, d1p[0], d2p, l, Pbuf + (w * 4 + 0) * 1024 + l);
  softmax_row(a1, d1p[1], d2p, l, Pbuf + (w * 4 + 1) * 1024 + l);
  softmax_row(a2, d1p[2], d2p, l, Pbuf + (w * 4 + 2) * 1024 + l);
  softmax_row(a3, d1p[3], d2p, l, Pbuf + (w * 4 + 3) * 1024 + l);
  __syncthreads();  // (intra-wave would suffice; barrier for safety)

  // S @ g : wave w computes rows w*4..w*4+3, lane = output channel
  const float* gp = gT + (size_t)n * 65536 + l;
  const float4* S0 = (const float4*)(Pbuf + (w * 4 + 0) * 1024);
  const float4* S1 = (const float4*)(Pbuf + (w * 4 + 1) * 1024);
  const float4* S2 = (const float4*)(Pbuf + (w * 4 + 2) * 1024);
  const float4* S3 = (const float4*)(Pbuf + (w * 4 + 3) * 1024);
  float y0 = 0.f, y1 = 0.f, y2 = 0.f, y3 = 0.f;
  for (int v4 = 0; v4 < 256; ++v4) {
    const float4 s0 = S0[v4], s1 = S1[v4], s2 = S2[v4], s3 = S3[v4];
    const float g0 = gp[(4 * v4 + 0) * 64];
    const float g1 = gp[(4 * v4 + 1) * 64];
    const float g2 = gp[(4 * v4 + 2) * 64];
    const float g3 = gp[(4 * v4 + 3) * 64];
    y0 += s0.x * g0 + s0.y * g1 + s0.z * g2 + s0.w * g3;
    y1 += s1.x * g0 + s1.y * g1 + s1.z * g2 + s1.w * g3;
    y2 += s2.x * g0 + s2.y * g1 + s2.z * g2 + s2.w * g3;
    y3 += s3.x * g0 + s3.y * g1 + s3.z * g2 + s3.w * g3;
  }
  const size_t yb = ((size_t)n * 4096 + q0 + w * 4) * 64 + l;
  yT[yb] = y0; yT[yb + 64] = y1; yT[yb + 128] = y2; yT[yb + 192] = y3;
}

// -------------------------- 9. z conv (pos-major input): yT[n][4096][64] ->
// z [n][128][4096] with zw [128][64] + zb
__global__ __launch_bounds__(256) void k_zconv(const float* __restrict__ yT,
                                               const float* __restrict__ zw,
                                               const float* __restrict__ zb,
                                               float* __restrict__ z) {
  __shared__ float yt[64][65];
  const int n = blockIdx.y, p0 = blockIdx.x * 64;
  const int t = threadIdx.x;
  {
    const float4* src = (const float4*)(yT + ((size_t)n * 4096 + p0) * 64);
    const int p2 = t >> 2, c2 = (t & 3) * 16;
#pragma unroll
    for (int k = 0; k < 4; ++k) {
      float4 v = src[t * 4 + k];
      yt[p2][c2 + 4 * k + 0] = v.x; yt[p2][c2 + 4 * k + 1] = v.y;
      yt[p2][c2 + 4 * k + 2] = v.z; yt[p2][c2 + 4 * k + 3] = v.w;
    }
  }
  __syncthreads();
  const int p = t & 63, og = t >> 6;  // outputs og*32 .. og*32+31
  float acc[32];
#pragma unroll
  for (int j = 0; j < 32; ++j) acc[j] = zb[og * 32 + j];
  const float4* zw4 = (const float4*)zw;
#pragma unroll
  for (int c4 = 0; c4 < 16; ++c4) {
    const float4 yv = make_float4(yt[p][4 * c4], yt[p][4 * c4 + 1], yt[p][4 * c4 + 2], yt[p][4 * c4 + 3]);
#pragma unroll
    for (int j = 0; j < 32; ++j) {
      const float4 wv = zw4[(og * 32 + j) * 16 + c4];
      acc[j] += yv.x * wv.x + yv.y * wv.y + yv.z * wv.z + yv.w * wv.w;
    }
  }
  const size_t zb0 = ((size_t)n * 128 + og * 32) * 4096 + p0 + p;
#pragma unroll
  for (int j = 0; j < 32; ++j) z[zb0 + (size_t)j * 4096] = acc[j];
}

// --------------- 10. final: out = x + bilinear_up(z, 64->256, align=True)
__global__ __launch_bounds__(256) void k_final(const float* __restrict__ x,
                                               const float* __restrict__ z,
                                               float* __restrict__ out) {
  const int n = blockIdx.z, c = blockIdx.y, Y = blockIdx.x, X = threadIdx.x;
  const float s = 63.f / 255.f;
  const float sy = Y * s, sx = X * s;
  const int ly = (int)sy, lx = (int)sx;
  const int hy = min(ly + 1, 63), hx = min(lx + 1, 63);
  const float fy = sy - ly, fx = sx - lx;
  const float* zp = z + (size_t)(n * 128 + c) * 4096;
  const float v = (1.f - fy) * ((1.f - fx) * zp[ly * 64 + lx] + fx * zp[ly * 64 + hx]) +
                  fy * ((1.f - fx) * zp[hy * 64 + lx] + fx * zp[hy * 64 + hx]);
  const size_t idx = ((size_t)(n * 128 + c) * 256 + Y) * 256 + X;
  out[idx] = x[idx] + v;
}

// ---------------------------------------------------------------- launcher
extern "C" void kernel_launch(void* const* d_in, const int* in_sizes, int n_in,
                              void* d_out, int out_size, void* d_ws, size_t ws_size,
                              hipStream_t stream) {
  const float* x       = (const float*)d_in[0];
  const float* depth   = (const float*)d_in[1];
  const float* down_w  = (const float*)d_in[2];
  const float* theta_w = (const float*)d_in[3];
  const float* theta_b = (const float*)d_in[4];
  const float* phi_w   = (const float*)d_in[5];
  const float* phi_b   = (const float*)d_in[6];
  const float* g_w     = (const float*)d_in[7];
  const float* g_b     = (const float*)d_in[8];
  const float* z_w     = (const float*)d_in[9];
  const float* z_b     = (const float*)d_in[10];
  const float* ppg_pw    = (const float*)d_in[11];
  const float* ppg_gamma = (const float*)d_in[12];
  const float* ppg_beta  = (const float*)d_in[13];
  const float* ppg_ow    = (const float*)d_in[14];
  const float* ppg_ob    = (const float*)d_in[15];
  const float* ppt_pw    = (const float*)d_in[16];
  const float* ppt_gamma = (const float*)d_in[17];
  const float* ppt_beta  = (const float*)d_in[18];
  const float* ppt_ow    = (const float*)d_in[19];
  const float* ppt_ob    = (const float*)d_in[20];
  const float* ppp_pw    = (const float*)d_in[21];
  const float* ppp_gamma = (const float*)d_in[22];
  const float* ppp_beta  = (const float*)d_in[23];
  const float* ppp_ow    = (const float*)d_in[24];
  const float* ppp_ob    = (const float*)d_in[25];

  float* ws = (float*)d_ws;
  float* xd       = ws;               // [4][128][4096]      (2097152)
  float* thetaT   = ws;               // alias after convs   (1048576)
  float* t_in     = ws + 2097152;     // [4][64][4096]       (1048576)
  float* zbuf     = ws + 2097152;     // alias after attn    (2097152)
  float* tmp      = ws + 3145728;     // [4][64][4096]       (1048576)
  float* phi_in   = ws + 4194304;     // [4][64][1024]       (262144)
  float* g_in     = ws + 4456448;     // [4][64][1024]       (262144)
  float* pooled_t = ws + 4718592;     // [4][64][85]
  float* pooled_p = ws + 4740352;
  float* pooled_g = ws + 4762112;
  float* q_t      = ws + 4783872;     // [4][85][16]
  float* q_p      = ws + 4789312;
  float* q_g      = ws + 4794752;
  float* phi_pp   = ws + 4800192;     // [4][64][1024]
  float* gT       = ws + 5062336;     // [4][1024][64]
  float* d1       = ws + 5324480;     // [4][4096]
  float* d2       = ws + 5340864;     // [4][1024]
  float* yT       = ws + 5344960;     // [4][4096][64]
  // total: 6393536 floats = 24.4 MiB

  dim3 b(256);
  k_down<<<dim3(16, 128, 4), b, 0, stream>>>(x, down_w, xd);
  k_conv_cm4<<<dim3(16, 16, 4), b, 0, stream>>>(xd, theta_w, theta_b, t_in, 128, 4096, 64);
  k_conv_cm4<<<dim3(16, 16, 4), b, 0, stream>>>(xd, phi_w, phi_b, tmp, 128, 4096, 64);
  k_maxpool2<<<dim3(4, 64, 4), b, 0, stream>>>(tmp, phi_in, 64, 64);
  k_conv_cm4<<<dim3(16, 16, 4), b, 0, stream>>>(xd, g_w, g_b, tmp, 128, 4096, 64);
  k_maxpool2<<<dim3(4, 64, 4), b, 0, stream>>>(tmp, g_in, 64, 64);
  k_dresize<<<dim3(20, 4), b, 0, stream>>>(depth, d1, d2);
  k_pool<<<dim3(256), b, 0, stream>>>(t_in, pooled_t, 64);
  k_pool<<<dim3(256), b, 0, stream>>>(phi_in, pooled_p, 32);
  k_pool<<<dim3(256), b, 0, stream>>>(g_in, pooled_g, 32);
  k_poolconv<<<dim3(4), b, 0, stream>>>(pooled_t, ppt_pw, ppt_gamma, ppt_beta, q_t);
  k_poolconv<<<dim3(4), b, 0, stream>>>(pooled_p, ppp_pw, ppp_gamma, ppp_beta, q_p);
  k_poolconv<<<dim3(4), b, 0, stream>>>(pooled_g, ppg_pw, ppg_gamma, ppg_beta, q_g);
  // theta: pos-major (attention consumes rows); writes over dead xd region
  k_ppfuse<<<dim3(64, 4), b, 0, stream>>>(t_in, q_t, ppt_ow, ppt_ob, thetaT, 64, 6, 1);
  k_ppfuse<<<dim3(16, 4), b, 0, stream>>>(phi_in, q_p, ppp_ow, ppp_ob, phi_pp, 32, 5, 0);
  k_ppfuse<<<dim3(16, 4), b, 0, stream>>>(g_in, q_g, ppg_ow, ppg_ob, gT, 32, 5, 1);
  k_attn<<<dim3(256, 4), b, 0, stream>>>(thetaT, phi_pp, gT, d1, d2, yT);
  k_zconv<<<dim3(64, 4), b, 0, stream>>>(yT, z_w, z_b, zbuf);
  k_final<<<dim3(256, 128, 4), b, 0, stream>>>(x, zbuf, (float*)d_out);
}

// Round 2
// 580.361 us; speedup vs baseline: 1.2891x; 1.2891x over previous
//
#include <hip/hip_runtime.h>
#include <hip/hip_bf16.h>

// Shapes: N=4, C=128, H=W=256, CC=64. x_down: 64x64. phi/g spatial: 32x32.
// Q = 4096 (64x64), V = 1024 (32x32).

typedef __bf16 bf16x8 __attribute__((ext_vector_type(8)));
typedef float f32x4 __attribute__((ext_vector_type(4)));

__device__ __forceinline__ ushort f2bf(float f) {
  uint b = __float_as_uint(f);
  uint r = (b + 0x7FFFu + ((b >> 16) & 1u)) >> 16;
  return (ushort)r;
}
__device__ __forceinline__ float red16max(float v) {
  v = fmaxf(v, __shfl_xor(v, 1, 64));
  v = fmaxf(v, __shfl_xor(v, 2, 64));
  v = fmaxf(v, __shfl_xor(v, 4, 64));
  v = fmaxf(v, __shfl_xor(v, 8, 64));
  return v;
}
__device__ __forceinline__ float red16sum(float v) {
  v += __shfl_xor(v, 1, 64);
  v += __shfl_xor(v, 2, 64);
  v += __shfl_xor(v, 4, 64);
  v += __shfl_xor(v, 8, 64);
  return v;
}

// ------------------------------------------------ 1. depthwise 4x4 stride-4
__global__ __launch_bounds__(256) void k_down(const float* __restrict__ x,
                                              const float* __restrict__ dw,
                                              float* __restrict__ xd) {
  const int n = blockIdx.z, c = blockIdx.y;
  const int p = blockIdx.x * 256 + threadIdx.x;  // 0..4095
  const int i = p >> 6, j = p & 63;
  const float* xp = x + (((size_t)(n * 128 + c) * 256) + i * 4) * 256 + j * 4;
  const float* wp = dw + c * 16;
  float acc = 0.f;
#pragma unroll
  for (int a = 0; a < 4; ++a) {
    float4 v = *(const float4*)(xp + a * 256);
    acc += v.x * wp[a * 4 + 0] + v.y * wp[a * 4 + 1] + v.z * wp[a * 4 + 2] + v.w * wp[a * 4 + 3];
  }
  xd[(size_t)(n * 128 + c) * 4096 + p] = acc;
}

// ------------------------------------- 2. conv1x1, channel-major, 4 outputs
__global__ __launch_bounds__(256) void k_conv_cm4(const float* __restrict__ in,
                                                  const float* __restrict__ w,
                                                  const float* __restrict__ b,
                                                  float* __restrict__ out,
                                                  int Cin, int P, int O) {
  const int n = blockIdx.z, o4 = blockIdx.y * 4;
  const int p = blockIdx.x * 256 + threadIdx.x;
  const float* ip = in + (size_t)n * Cin * P + p;
  float a0 = b[o4], a1 = b[o4 + 1], a2 = b[o4 + 2], a3 = b[o4 + 3];
  const float* w0 = w + (size_t)o4 * Cin;
  const float* w1 = w0 + Cin;
  const float* w2 = w1 + Cin;
  const float* w3 = w2 + Cin;
  for (int c = 0; c < Cin; ++c) {
    const float v = ip[(size_t)c * P];
    a0 += v * w0[c]; a1 += v * w1[c]; a2 += v * w2[c]; a3 += v * w3[c];
  }
  size_t ob = ((size_t)n * O + o4) * P + p;
  out[ob] = a0; out[ob + P] = a1; out[ob + 2 * (size_t)P] = a2; out[ob + 3 * (size_t)P] = a3;
}

// ------------------------------------------------------------- 3. maxpool2
__global__ __launch_bounds__(256) void k_maxpool2(const float* __restrict__ in,
                                                  float* __restrict__ out,
                                                  int H, int W) {
  const int n = blockIdx.z, c = blockIdx.y;
  const int oh = H / 2, ow = W / 2;
  const int p = blockIdx.x * 256 + threadIdx.x;
  if (p >= oh * ow) return;
  const int i = p / ow, j = p % ow;
  const float* ip = in + ((size_t)(n * 64 + c) * H + 2 * i) * W + 2 * j;
  float m = fmaxf(fmaxf(ip[0], ip[1]), fmaxf(ip[W], ip[W + 1]));
  out[((size_t)(n * 64 + c) * oh + i) * ow + j] = m;
}

// -------------------------------------- 4. pyramid avg-pools (8,4,2,1 grid)
__global__ __launch_bounds__(256) void k_pool(const float* __restrict__ in,
                                              float* __restrict__ pooled, int H) {
  __shared__ float red[64][4];
  __shared__ float s8[64];
  const int blk = blockIdx.x;
  const int n = blk >> 6, c = blk & 63;
  const int t = threadIdx.x;
  const int cell = t & 63, part = t >> 6;
  const int gy = cell >> 3, gx = cell & 7;
  const int k = H >> 3;
  const int rpp = (k >> 2) ? (k >> 2) : 1;
  const float* base = in + (size_t)(n * 64 + c) * H * H;
  float s = 0.f;
  for (int r = 0; r < rpp; ++r) {
    const int y = gy * k + part * rpp + r;
    const float* rp = base + y * H + gx * k;
    for (int xx = 0; xx < k; xx += 4) {
      float4 v = *(const float4*)(rp + xx);
      s += v.x + v.y + v.z + v.w;
    }
  }
  red[cell][part] = s;
  __syncthreads();
  if (t < 64) s8[t] = red[t][0] + red[t][1] + red[t][2] + red[t][3];
  __syncthreads();
  float* pout = pooled + (size_t)(n * 64 + c) * 85;
  const float inv = 1.f / (float)(k * k);
  if (t < 64) {
    pout[t] = s8[t] * inv;
  } else if (t < 80) {
    const int i2 = t - 64, gy2 = i2 >> 2, gx2 = i2 & 3;
    float v = s8[(2 * gy2) * 8 + 2 * gx2] + s8[(2 * gy2) * 8 + 2 * gx2 + 1] +
              s8[(2 * gy2 + 1) * 8 + 2 * gx2] + s8[(2 * gy2 + 1) * 8 + 2 * gx2 + 1];
    pout[64 + i2] = v * inv * 0.25f;
  } else if (t < 84) {
    const int i1 = t - 80, gy1 = i1 >> 1, gx1 = i1 & 1;
    float v = 0.f;
    for (int yy = 0; yy < 4; ++yy)
      for (int xx = 0; xx < 4; ++xx) v += s8[(gy1 * 4 + yy) * 8 + gx1 * 4 + xx];
    pout[80 + i1] = v * inv * 0.0625f;
  } else if (t == 84) {
    float v = 0.f;
    for (int i = 0; i < 64; ++i) v += s8[i];
    pout[84] = v * inv * (1.f / 64.f);
  }
}

// -------------------- 5. pyramid level conv (64->16) + BN(eval) + ReLU
__global__ __launch_bounds__(256) void k_poolconv(const float* __restrict__ pooled,
                                                  const float* __restrict__ pw,
                                                  const float* __restrict__ gamma,
                                                  const float* __restrict__ beta,
                                                  float* __restrict__ qout) {
  const int n = blockIdx.x;
  const float bnscale = 0.9999950000374997f;  // 1/sqrt(1+1e-5)
  for (int idx = threadIdx.x; idx < 85 * 16; idx += 256) {
    const int pos = idx >> 4, o = idx & 15;
    const int s = (pos < 64) ? 0 : (pos < 80) ? 1 : (pos < 84) ? 2 : 3;
    const float* pp = pooled + (size_t)n * 64 * 85 + pos;
    const float* wp = pw + (s * 16 + o) * 64;
    float acc = 0.f;
    for (int c = 0; c < 64; ++c) acc += pp[c * 85] * wp[c];
    acc = acc * bnscale * gamma[s * 16 + o] + beta[s * 16 + o];
    qout[((size_t)n * 85 + pos) * 16 + o] = fmaxf(acc, 0.f);
  }
}

// --------- 6. pyramid fuse: bilinear-up(4 scales) + concat + conv128->64
// out (bf16 as ushort): pos_major ? [n][S*S][64] : [n][64][S*S]
__global__ __launch_bounds__(256) void k_ppfuse(const float* __restrict__ in,
                                                const float* __restrict__ q,
                                                const float* __restrict__ ow,
                                                const float* __restrict__ ob,
                                                ushort* __restrict__ out,
                                                int S, int lw, int pos_major) {
  __shared__ float bl[64][65];
  __shared__ float til[64][65];
  const int n = blockIdx.y;
  const int P = S * S;
  const int pixbase = blockIdx.x * 64;
  const int t = threadIdx.x;
  const int p = t & 63, sc = t >> 6;

  {
    const int pg = pixbase + p;
    const int y = pg >> lw, x = pg & (S - 1);
    const int ps = 8 >> sc;
    const int off = (sc == 0) ? 0 : (sc == 1) ? 64 : (sc == 2) ? 80 : 84;
    const float scale = (float)ps / (float)S;
    float syf = fminf(fmaxf((y + 0.5f) * scale - 0.5f, 0.f), (float)(ps - 1));
    float sxf = fminf(fmaxf((x + 0.5f) * scale - 0.5f, 0.f), (float)(ps - 1));
    const int ly = (int)syf, lx = (int)sxf;
    const int hy = min(ly + 1, ps - 1), hx = min(lx + 1, ps - 1);
    const float fy = syf - ly, fx = sxf - lx;
    const float w00 = (1.f - fy) * (1.f - fx), w01 = (1.f - fy) * fx;
    const float w10 = fy * (1.f - fx), w11 = fy * fx;
    const float* qn = q + (size_t)n * 85 * 16;
    const float4* r00 = (const float4*)(qn + (off + ly * ps + lx) * 16);
    const float4* r01 = (const float4*)(qn + (off + ly * ps + hx) * 16);
    const float4* r10 = (const float4*)(qn + (off + hy * ps + lx) * 16);
    const float4* r11 = (const float4*)(qn + (off + hy * ps + hx) * 16);
#pragma unroll
    for (int k = 0; k < 4; ++k) {
      float4 v00 = r00[k], v01 = r01[k], v10 = r10[k], v11 = r11[k];
      bl[p][sc * 16 + 4 * k + 0] = w00 * v00.x + w01 * v01.x + w10 * v10.x + w11 * v11.x;
      bl[p][sc * 16 + 4 * k + 1] = w00 * v00.y + w01 * v01.y + w10 * v10.y + w11 * v11.y;
      bl[p][sc * 16 + 4 * k + 2] = w00 * v00.z + w01 * v01.z + w10 * v10.z + w11 * v11.z;
      bl[p][sc * 16 + 4 * k + 3] = w00 * v00.w + w01 * v01.w + w10 * v10.w + w11 * v11.w;
    }
  }
  {
    const float* ip = in + (size_t)n * 64 * P + pixbase + p;
#pragma unroll
    for (int k = 0; k < 16; ++k) {
      const int c = sc + 4 * k;
      til[p][c] = ip[(size_t)c * P];
    }
  }
  __syncthreads();
  const int obase = sc * 16;
  float acc[16];
#pragma unroll
  for (int j = 0; j < 16; ++j) acc[j] = ob[obase + j];
  const float4* ow4 = (const float4*)ow;
#pragma unroll
  for (int c4 = 0; c4 < 16; ++c4) {
    const float4 tv = make_float4(til[p][4 * c4], til[p][4 * c4 + 1], til[p][4 * c4 + 2], til[p][4 * c4 + 3]);
    const float4 bv = make_float4(bl[p][4 * c4], bl[p][4 * c4 + 1], bl[p][4 * c4 + 2], bl[p][4 * c4 + 3]);
#pragma unroll
    for (int j = 0; j < 16; ++j) {
      const float4 wv = ow4[(obase + j) * 32 + c4];
      const float4 wb = ow4[(obase + j) * 32 + 16 + c4];
      acc[j] += tv.x * wv.x + tv.y * wv.y + tv.z * wv.z + tv.w * wv.w +
                bv.x * wb.x + bv.y * wb.y + bv.z * wb.z + bv.w * wb.w;
    }
  }
  if (pos_major) {
    __syncthreads();
#pragma unroll
    for (int j = 0; j < 16; ++j) til[p][obase + j] = acc[j];
    __syncthreads();
    const int p2 = t >> 2, c2 = (t & 3) * 16;
    uint pk[8];
#pragma unroll
    for (int i = 0; i < 8; ++i)
      pk[i] = (uint)f2bf(til[p2][c2 + 2 * i]) | ((uint)f2bf(til[p2][c2 + 2 * i + 1]) << 16);
    uint4* dst = (uint4*)(out + ((size_t)n * P + pixbase) * 64 + (size_t)t * 16);
    dst[0] = make_uint4(pk[0], pk[1], pk[2], pk[3]);
    dst[1] = make_uint4(pk[4], pk[5], pk[6], pk[7]);
  } else {
#pragma unroll
    for (int j = 0; j < 16; ++j)
      out[((size_t)n * 64 + obase + j) * P + pixbase + p] = f2bf(acc[j]);
  }
}

// ------------------------- 7. depth map resizes (align_corners=True), 1 ch
__global__ __launch_bounds__(256) void k_dresize(const float* __restrict__ depth,
                                                 float* __restrict__ d1,
                                                 float* __restrict__ d2) {
  const int n = blockIdx.y;
  const int bx = blockIdx.x;
  const float* dp = depth + (size_t)n * 65536;
  int i, j, idx;
  float scale;
  float* outp;
  if (bx < 16) {
    idx = bx * 256 + threadIdx.x;
    i = idx >> 6; j = idx & 63;
    scale = 255.f / 63.f;
    outp = d1 + (size_t)n * 4096;
  } else {
    idx = (bx - 16) * 256 + threadIdx.x;
    i = idx >> 5; j = idx & 31;
    scale = 255.f / 31.f;
    outp = d2 + (size_t)n * 1024;
  }
  const float sy = i * scale, sx = j * scale;
  const int ly = (int)sy, lx = (int)sx;
  const int hy = min(ly + 1, 255), hx = min(lx + 1, 255);
  const float fy = sy - ly, fx = sx - lx;
  const float v = (1.f - fy) * ((1.f - fx) * dp[ly * 256 + lx] + fx * dp[ly * 256 + hx]) +
                  fy * ((1.f - fx) * dp[hy * 256 + lx] + fx * dp[hy * 256 + hx]);
  outp[idx] = v;
}

// --------------------------------------------- 8. attention (MFMA, bf16)
// thetaB [n][4096][64] bf16, phiB [n][1024][64] bf16 (v-major),
// gB [n][64][1024] bf16 (c-major), d1 [n][4096], d2 [n][1024] -> yT [n][4096][64] f32
__global__ __launch_bounds__(256) void k_attn(const ushort* __restrict__ thetaB,
                                              const ushort* __restrict__ phiB,
                                              const ushort* __restrict__ gB,
                                              const float* __restrict__ d1,
                                              const float* __restrict__ d2,
                                              float* __restrict__ yT) {
  // s tile: 4 waves x 16 rows x 264 bf16 (stride-padded for b128 reads) = 33792 B
  __shared__ __align__(16) char smem[4 * 16 * 264 * 2];
  __shared__ float redl[4][16][4];
  __shared__ float spv[16];
  ushort* sbuf = (ushort*)smem;
  float* ypart = (float*)smem;  // [4][16][68] aliases sbuf (after barrier)

  const int n = blockIdx.y, q0 = blockIdx.x * 16;
  const int t = threadIdx.x, w = t >> 6, l = t & 63;
  const int lane16 = l & 15, quad = l >> 4;
  const int v0 = w * 256;

  // ---- GEMM1: a[16 x 256] = theta[16 x 64] * phi[64 x 256]
  f32x4 acc[16];
#pragma unroll
  for (int i = 0; i < 16; ++i) acc[i] = (f32x4){0.f, 0.f, 0.f, 0.f};
  const ushort* thA = thetaB + ((size_t)n * 4096 + q0 + lane16) * 64 + quad * 8;
  const ushort* phB = phiB + ((size_t)n * 1024 + v0 + lane16) * 64 + quad * 8;
#pragma unroll
  for (int ks = 0; ks < 2; ++ks) {
    bf16x8 av = *(const bf16x8*)(thA + ks * 32);
#pragma unroll
    for (int t16 = 0; t16 < 16; ++t16) {
      bf16x8 bv = *(const bf16x8*)(phB + t16 * 16 * 64 + ks * 32);
      acc[t16] = __builtin_amdgcn_mfma_f32_16x16x32_bf16(av, bv, acc[t16], 0, 0, 0);
    }
  }

  // lane owns rows q0+quad*4+r (r=0..3), cols v0+t16*16+lane16
  const float e6 = 1e-6f;
  float dq[4], iq[4];
  const float* d1p = d1 + (size_t)n * 4096 + q0 + quad * 4;
#pragma unroll
  for (int r = 0; r < 4; ++r) { dq[r] = d1p[r]; iq[r] = 1.f / (dq[r] + e6); }
  const float* d2p = d2 + (size_t)n * 1024 + v0 + lane16;

  // round 1: global row max of a (Rd and final softmax need no max: args in (0,1])
  float mx[4] = {-1e30f, -1e30f, -1e30f, -1e30f};
#pragma unroll
  for (int t16 = 0; t16 < 16; ++t16)
#pragma unroll
    for (int r = 0; r < 4; ++r) mx[r] = fmaxf(mx[r], acc[t16][r]);
#pragma unroll
  for (int r = 0; r < 4; ++r) mx[r] = red16max(mx[r]);
  if (lane16 == 0)
#pragma unroll
    for (int r = 0; r < 4; ++r) redl[w][quad * 4 + r][0] = mx[r];
  __syncthreads();
  float m[4];
#pragma unroll
  for (int r = 0; r < 4; ++r) {
    float v = redl[0][quad * 4 + r][0];
    v = fmaxf(v, redl[1][quad * 4 + r][0]);
    v = fmaxf(v, redl[2][quad * 4 + r][0]);
    m[r] = fmaxf(v, redl[3][quad * 4 + r][0]);
  }

  // round 2: ea=exp(a-m), er=exp(r_dv); ar=ea*er; sums se,sr
  float se[4] = {0.f, 0.f, 0.f, 0.f}, sr[4] = {0.f, 0.f, 0.f, 0.f};
#pragma unroll
  for (int t16 = 0; t16 < 16; ++t16) {
    const float dd = d2p[t16 * 16];
    const float idd = 1.f / (dd + e6);
#pragma unroll
    for (int r = 0; r < 4; ++r) {
      const float rv = fminf(dq[r] * idd, dd * iq[r]);
      const float er = __expf(rv);
      const float ea = __expf(acc[t16][r] - m[r]);
      acc[t16][r] = ea * er;
      se[r] += ea; sr[r] += er;
    }
  }
#pragma unroll
  for (int r = 0; r < 4; ++r) { se[r] = red16sum(se[r]); sr[r] = red16sum(sr[r]); }
  if (lane16 == 0)
#pragma unroll
    for (int r = 0; r < 4; ++r) {
      redl[w][quad * 4 + r][1] = se[r];
      redl[w][quad * 4 + r][2] = sr[r];
    }
  __syncthreads();
  float U[4];
#pragma unroll
  for (int r = 0; r < 4; ++r) {
    const int row = quad * 4 + r;
    const float set = redl[0][row][1] + redl[1][row][1] + redl[2][row][1] + redl[3][row][1];
    const float srt = redl[0][row][2] + redl[1][row][2] + redl[2][row][2] + redl[3][row][2];
    U[r] = 1.f / (set * srt);
  }

  // round 3: s = exp(U*ar) (U*ar = Ra*Rd in (0,1]); sum sp
  float sp[4] = {0.f, 0.f, 0.f, 0.f};
#pragma unroll
  for (int t16 = 0; t16 < 16; ++t16)
#pragma unroll
    for (int r = 0; r < 4; ++r) {
      const float s_ = __expf(U[r] * acc[t16][r]);
      acc[t16][r] = s_;
      sp[r] += s_;
    }
#pragma unroll
  for (int r = 0; r < 4; ++r) sp[r] = red16sum(sp[r]);
  if (lane16 == 0)
#pragma unroll
    for (int r = 0; r < 4; ++r) redl[w][quad * 4 + r][3] = sp[r];
  __syncthreads();
  if (w == 0 && lane16 == 0)
#pragma unroll
    for (int r = 0; r < 4; ++r) {
      const int row = quad * 4 + r;
      spv[row] = 1.f / (redl[0][row][3] + redl[1][row][3] + redl[2][row][3] + redl[3][row][3]);
    }

  // write s (unnormalized, in (0,e]) to LDS as bf16 in A-layout source [m][k]
  ushort* srow = sbuf + w * (16 * 264);
#pragma unroll
  for (int t16 = 0; t16 < 16; ++t16)
#pragma unroll
    for (int r = 0; r < 4; ++r)
      srow[(quad * 4 + r) * 264 + t16 * 16 + lane16] = f2bf(acc[t16][r]);
  __syncthreads();

  // ---- GEMM2: y_partial[16 x 64] = s[16 x 256] * g[256 x 64]
  f32x4 acc2[4];
#pragma unroll
  for (int i = 0; i < 4; ++i) acc2[i] = (f32x4){0.f, 0.f, 0.f, 0.f};
  const ushort* sA = sbuf + w * (16 * 264) + lane16 * 264 + quad * 8;
  const ushort* gq = gB + (size_t)n * 65536 + v0 + quad * 8;
#pragma unroll
  for (int kk = 0; kk < 8; ++kk) {
    bf16x8 av = *(const bf16x8*)(sA + kk * 32);
#pragma unroll
    for (int tn = 0; tn < 4; ++tn) {
      bf16x8 bv = *(const bf16x8*)(gq + (size_t)(tn * 16 + lane16) * 1024 + kk * 32);
      acc2[tn] = __builtin_amdgcn_mfma_f32_16x16x32_bf16(av, bv, acc2[tn], 0, 0, 0);
    }
  }
  __syncthreads();  // all s reads done; ypart aliases sbuf
  float* yp = ypart + w * (16 * 68);
#pragma unroll
  for (int tn = 0; tn < 4; ++tn)
#pragma unroll
    for (int r = 0; r < 4; ++r)
      yp[(quad * 4 + r) * 68 + tn * 16 + lane16] = acc2[tn][r];
  __syncthreads();
  // cross-wave K-combine + 1/sp scale + store (pos-major fp32)
  const int row = t >> 4, c0 = (t & 15) * 4;
  float4 s0 = *(const float4*)(ypart + 0 * 1088 + row * 68 + c0);
  float4 s1 = *(const float4*)(ypart + 1 * 1088 + row * 68 + c0);
  float4 s2 = *(const float4*)(ypart + 2 * 1088 + row * 68 + c0);
  float4 s3 = *(const float4*)(ypart + 3 * 1088 + row * 68 + c0);
  const float isp = spv[row];
  float4 o;
  o.x = (s0.x + s1.x + s2.x + s3.x) * isp;
  o.y = (s0.y + s1.y + s2.y + s3.y) * isp;
  o.z = (s0.z + s1.z + s2.z + s3.z) * isp;
  o.w = (s0.w + s1.w + s2.w + s3.w) * isp;
  *(float4*)(yT + ((size_t)n * 4096 + q0 + row) * 64 + c0) = o;
}

// -------------------------- 9. z conv: yT[n][4096][64] -> z [n][128][4096]
__global__ __launch_bounds__(256) void k_zconv(const float* __restrict__ yT,
                                               const float* __restrict__ zw,
                                               const float* __restrict__ zb,
                                               float* __restrict__ z) {
  __shared__ float yt[64][65];
  const int n = blockIdx.y, p0 = blockIdx.x * 64;
  const int t = threadIdx.x;
  {
    const float4* src = (const float4*)(yT + ((size_t)n * 4096 + p0) * 64);
    const int p2 = t >> 2, c2 = (t & 3) * 16;
#pragma unroll
    for (int k = 0; k < 4; ++k) {
      float4 v = src[t * 4 + k];
      yt[p2][c2 + 4 * k + 0] = v.x; yt[p2][c2 + 4 * k + 1] = v.y;
      yt[p2][c2 + 4 * k + 2] = v.z; yt[p2][c2 + 4 * k + 3] = v.w;
    }
  }
  __syncthreads();
  const int p = t & 63, og = t >> 6;
  float acc[32];
#pragma unroll
  for (int j = 0; j < 32; ++j) acc[j] = zb[og * 32 + j];
  const float4* zw4 = (const float4*)zw;
#pragma unroll
  for (int c4 = 0; c4 < 16; ++c4) {
    const float4 yv = make_float4(yt[p][4 * c4], yt[p][4 * c4 + 1], yt[p][4 * c4 + 2], yt[p][4 * c4 + 3]);
#pragma unroll
    for (int j = 0; j < 32; ++j) {
      const float4 wv = zw4[(og * 32 + j) * 16 + c4];
      acc[j] += yv.x * wv.x + yv.y * wv.y + yv.z * wv.z + yv.w * wv.w;
    }
  }
  const size_t zb0 = ((size_t)n * 128 + og * 32) * 4096 + p0 + p;
#pragma unroll
  for (int j = 0; j < 32; ++j) z[zb0 + (size_t)j * 4096] = acc[j];
}

// --------------- 10. final: out = x + bilinear_up(z, 64->256, align=True)
__global__ __launch_bounds__(256) void k_final(const float* __restrict__ x,
                                               const float* __restrict__ z,
                                               float* __restrict__ out) {
  const int n = blockIdx.z, c = blockIdx.y;
  const int Y = blockIdx.x * 4 + (threadIdx.x >> 6);
  const int X0 = (threadIdx.x & 63) * 4;
  const float s = 63.f / 255.f;
  const float sy = Y * s;
  const int ly = (int)sy;
  const int hy = min(ly + 1, 63);
  const float fy = sy - ly;
  const float* zp = z + (size_t)(n * 128 + c) * 4096;
  float4 o;
  float* po = &o.x;
#pragma unroll
  for (int k = 0; k < 4; ++k) {
    const float sx = (X0 + k) * s;
    const int lx = (int)sx;
    const int hx = min(lx + 1, 63);
    const float fx = sx - lx;
    po[k] = (1.f - fy) * ((1.f - fx) * zp[ly * 64 + lx] + fx * zp[ly * 64 + hx]) +
            fy * ((1.f - fx) * zp[hy * 64 + lx] + fx * zp[hy * 64 + hx]);
  }
  const size_t idx = ((size_t)(n * 128 + c) * 256 + Y) * 256 + X0;
  const float4 xv = *(const float4*)(x + idx);
  o.x += xv.x; o.y += xv.y; o.z += xv.z; o.w += xv.w;
  *(float4*)(out + idx) = o;
}

// ---------------------------------------------------------------- launcher
extern "C" void kernel_launch(void* const* d_in, const int* in_sizes, int n_in,
                              void* d_out, int out_size, void* d_ws, size_t ws_size,
                              hipStream_t stream) {
  const float* x       = (const float*)d_in[0];
  const float* depth   = (const float*)d_in[1];
  const float* down_w  = (const float*)d_in[2];
  const float* theta_w = (const float*)d_in[3];
  const float* theta_b = (const float*)d_in[4];
  const float* phi_w   = (const float*)d_in[5];
  const float* phi_b   = (const float*)d_in[6];
  const float* g_w     = (const float*)d_in[7];
  const float* g_b     = (const float*)d_in[8];
  const float* z_w     = (const float*)d_in[9];
  const float* z_b     = (const float*)d_in[10];
  const float* ppg_pw    = (const float*)d_in[11];
  const float* ppg_gamma = (const float*)d_in[12];
  const float* ppg_beta  = (const float*)d_in[13];
  const float* ppg_ow    = (const float*)d_in[14];
  const float* ppg_ob    = (const float*)d_in[15];
  const float* ppt_pw    = (const float*)d_in[16];
  const float* ppt_gamma = (const float*)d_in[17];
  const float* ppt_beta  = (const float*)d_in[18];
  const float* ppt_ow    = (const float*)d_in[19];
  const float* ppt_ob    = (const float*)d_in[20];
  const float* ppp_pw    = (const float*)d_in[21];
  const float* ppp_gamma = (const float*)d_in[22];
  const float* ppp_beta  = (const float*)d_in[23];
  const float* ppp_ow    = (const float*)d_in[24];
  const float* ppp_ob    = (const float*)d_in[25];

  float* ws = (float*)d_ws;
  float* xd       = ws;               // [4][128][4096]; zbuf aliases later
  float* zbuf     = ws;
  float* t_in     = ws + 2097152;     // [4][64][4096]; yT aliases later
  float* yT       = ws + 2097152;
  float* tmp      = ws + 3145728;     // [4][64][4096]
  float* phi_in   = ws + 4194304;     // [4][64][1024]
  float* g_in     = ws + 4456448;     // [4][64][1024]
  float* pooled_t = ws + 4718592;     // [4][64][85]
  float* pooled_p = ws + 4740352;
  float* pooled_g = ws + 4762112;
  float* q_t      = ws + 4783872;     // [4][85][16]
  float* q_p      = ws + 4789312;
  float* q_g      = ws + 4794752;
  ushort* thetaB  = (ushort*)(ws + 4800192);  // [4][4096][64] bf16
  ushort* phiB    = (ushort*)(ws + 5324480);  // [4][1024][64] bf16
  ushort* gB      = (ushort*)(ws + 5455552);  // [4][64][1024] bf16
  float* d1       = ws + 5586624;     // [4][4096]
  float* d2       = ws + 5603008;     // [4][1024]
  // total: 5607104 floats = 21.4 MiB

  dim3 b(256);
  k_down<<<dim3(16, 128, 4), b, 0, stream>>>(x, down_w, xd);
  k_conv_cm4<<<dim3(16, 16, 4), b, 0, stream>>>(xd, theta_w, theta_b, t_in, 128, 4096, 64);
  k_conv_cm4<<<dim3(16, 16, 4), b, 0, stream>>>(xd, phi_w, phi_b, tmp, 128, 4096, 64);
  k_maxpool2<<<dim3(4, 64, 4), b, 0, stream>>>(tmp, phi_in, 64, 64);
  k_conv_cm4<<<dim3(16, 16, 4), b, 0, stream>>>(xd, g_w, g_b, tmp, 128, 4096, 64);
  k_maxpool2<<<dim3(4, 64, 4), b, 0, stream>>>(tmp, g_in, 64, 64);
  k_dresize<<<dim3(20, 4), b, 0, stream>>>(depth, d1, d2);
  k_pool<<<dim3(256), b, 0, stream>>>(t_in, pooled_t, 64);
  k_pool<<<dim3(256), b, 0, stream>>>(phi_in, pooled_p, 32);
  k_pool<<<dim3(256), b, 0, stream>>>(g_in, pooled_g, 32);
  k_poolconv<<<dim3(4), b, 0, stream>>>(pooled_t, ppt_pw, ppt_gamma, ppt_beta, q_t);
  k_poolconv<<<dim3(4), b, 0, stream>>>(pooled_p, ppp_pw, ppp_gamma, ppp_beta, q_p);
  k_poolconv<<<dim3(4), b, 0, stream>>>(pooled_g, ppg_pw, ppg_gamma, ppg_beta, q_g);
  k_ppfuse<<<dim3(64, 4), b, 0, stream>>>(t_in, q_t, ppt_ow, ppt_ob, thetaB, 64, 6, 1);
  k_ppfuse<<<dim3(16, 4), b, 0, stream>>>(phi_in, q_p, ppp_ow, ppp_ob, phiB, 32, 5, 1);
  k_ppfuse<<<dim3(16, 4), b, 0, stream>>>(g_in, q_g, ppg_ow, ppg_ob, gB, 32, 5, 0);
  k_attn<<<dim3(256, 4), b, 0, stream>>>(thetaB, phiB, gB, d1, d2, yT);
  k_zconv<<<dim3(64, 4), b, 0, stream>>>(yT, z_w, z_b, zbuf);
  k_final<<<dim3(64, 128, 4), b, 0, stream>>>(x, zbuf, (float*)d_out);
}

// Round 3
// 471.039 us; speedup vs baseline: 1.5883x; 1.2321x over previous
//
#include <hip/hip_runtime.h>
#include <hip/hip_bf16.h>

// Shapes: N=4, C=128, H=W=256, CC=64. x_down: 64x64. phi/g spatial: 32x32.
// Q = 4096 (64x64), V = 1024 (32x32).

typedef __bf16 bf16x8 __attribute__((ext_vector_type(8)));
typedef float f32x4 __attribute__((ext_vector_type(4)));

__device__ __forceinline__ ushort f2bf(float f) {
  uint b = __float_as_uint(f);
  uint r = (b + 0x7FFFu + ((b >> 16) & 1u)) >> 16;
  return (ushort)r;
}
__device__ __forceinline__ float red16max(float v) {
  v = fmaxf(v, __shfl_xor(v, 1, 64));
  v = fmaxf(v, __shfl_xor(v, 2, 64));
  v = fmaxf(v, __shfl_xor(v, 4, 64));
  v = fmaxf(v, __shfl_xor(v, 8, 64));
  return v;
}
__device__ __forceinline__ float red16sum(float v) {
  v += __shfl_xor(v, 1, 64);
  v += __shfl_xor(v, 2, 64);
  v += __shfl_xor(v, 4, 64);
  v += __shfl_xor(v, 8, 64);
  return v;
}

// ---------------- 1. depthwise 4x4 stride-4 (+ weight prepack tail block)
// x [n][128][256][256] * dw [128][4][4] -> xd [n][128][64][64]
// block 8192: Wb[192][128] bf16 = concat(theta_w, phi_w, g_w); Bc[192] = biases
__global__ __launch_bounds__(256) void k_down(const float* __restrict__ x,
                                              const float* __restrict__ dw,
                                              float* __restrict__ xd,
                                              const float* __restrict__ tw,
                                              const float* __restrict__ tb,
                                              const float* __restrict__ pw,
                                              const float* __restrict__ pb,
                                              const float* __restrict__ gw,
                                              const float* __restrict__ gb,
                                              ushort* __restrict__ Wb,
                                              float* __restrict__ Bc) {
  const int bid = blockIdx.x;
  if (bid == 8192) {
    for (int i = threadIdx.x; i < 192 * 128; i += 256) {
      const int o = i >> 7, c = i & 127;
      const float v = (o < 64) ? tw[o * 128 + c]
                    : (o < 128) ? pw[(o - 64) * 128 + c]
                                : gw[(o - 128) * 128 + c];
      Wb[i] = f2bf(v);
    }
    if (threadIdx.x < 192) {
      const int o = threadIdx.x;
      Bc[o] = (o < 64) ? tb[o] : (o < 128) ? pb[o - 64] : gb[o - 128];
    }
    return;
  }
  const int n = bid >> 11, c = (bid >> 4) & 127;
  const int p = (bid & 15) * 256 + threadIdx.x;  // 0..4095
  const int i = p >> 6, j = p & 63;
  const float* xp = x + (((size_t)(n * 128 + c) * 256) + i * 4) * 256 + j * 4;
  const float* wp = dw + c * 16;
  float acc = 0.f;
#pragma unroll
  for (int a = 0; a < 4; ++a) {
    float4 v = *(const float4*)(xp + a * 256);
    acc += v.x * wp[a * 4 + 0] + v.y * wp[a * 4 + 1] + v.z * wp[a * 4 + 2] + v.w * wp[a * 4 + 3];
  }
  xd[(size_t)(n * 128 + c) * 4096 + p] = acc;
}

// ---------------- 2. fused convs (MFMA) + maxpools
// xd [n][128][4096] -> t_in [n][64][4096] f32; phi_in/g_in [n][64][1024] f32 (maxpooled)
// block: 64 px = out rows (2rp, 2rp+1) x cols jh*32..+31. 256 blocks.
__global__ __launch_bounds__(256) void k_cfuse(const float* __restrict__ xd,
                                               const ushort* __restrict__ Wb,
                                               const float* __restrict__ Bc,
                                               float* __restrict__ t_in,
                                               float* __restrict__ phi_in,
                                               float* __restrict__ g_in) {
  __shared__ __align__(16) ushort xs[64 * 132];  // [px][K=128 bf16, pad to 132]
  const int bid = blockIdx.x;
  const int n = bid >> 6, rp = (bid >> 1) & 31, jh = bid & 1;
  const int t = threadIdx.x, w = t >> 6, l = t & 63;
  // stage xd tile -> bf16 LDS (B-operand layout: [px][k] contiguous in k)
  {
    const int rr = l >> 5, col = l & 31;
    const int gpx = (2 * rp + rr) * 64 + jh * 32 + col;
    const float* xsrc = xd + (size_t)n * 128 * 4096 + gpx;
#pragma unroll
    for (int k = 0; k < 32; ++k) {
      const int c = w * 32 + k;
      xs[l * 132 + c] = f2bf(xsrc[(size_t)c * 4096]);
    }
  }
  __syncthreads();
  const int lane16 = l & 15, quad = l >> 4;
  f32x4 acc[3][4];
#pragma unroll
  for (int i = 0; i < 3; ++i)
#pragma unroll
    for (int nt = 0; nt < 4; ++nt) acc[i][nt] = (f32x4){0.f, 0.f, 0.f, 0.f};
#pragma unroll
  for (int ks = 0; ks < 4; ++ks) {
    bf16x8 a[3];
#pragma unroll
    for (int i = 0; i < 3; ++i)
      a[i] = *(const bf16x8*)(Wb + (size_t)((3 * w + i) * 16 + lane16) * 128 + ks * 32 + quad * 8);
#pragma unroll
    for (int nt = 0; nt < 4; ++nt) {
      bf16x8 b = *(const bf16x8*)(xs + (nt * 16 + lane16) * 132 + ks * 32 + quad * 8);
#pragma unroll
      for (int i = 0; i < 3; ++i)
        acc[i][nt] = __builtin_amdgcn_mfma_f32_16x16x32_bf16(a[i], b, acc[i][nt], 0, 0, 0);
    }
  }
  // epilogue: o = tile*16 + quad*4 + reg, px = nt*16 + lane16 (r=px>>5, c=px&31)
#pragma unroll
  for (int i = 0; i < 3; ++i) {
    const int tile = 3 * w + i;
    const int ob = tile * 16 + quad * 4;
    float bcv[4];
#pragma unroll
    for (int reg = 0; reg < 4; ++reg) bcv[reg] = Bc[ob + reg];
    if (tile < 4) {  // theta: direct store ch-major
#pragma unroll
      for (int nt = 0; nt < 4; ++nt) {
        const int px = nt * 16 + lane16, rr = px >> 5, cc = px & 31;
        const size_t base = (size_t)(n * 64) * 4096 + (2 * rp + rr) * 64 + jh * 32 + cc;
#pragma unroll
        for (int reg = 0; reg < 4; ++reg)
          t_in[base + (size_t)(ob + reg) * 4096] = acc[i][nt][reg] + bcv[reg];
      }
    } else {  // phi/g: maxpool 2x2 then store
      const int o64 = ob - 64;  // 0..63 phi, 64..127 g (tile-uniform branch)
      float* outp = (o64 < 64) ? phi_in : g_in;
      const int oo = (o64 < 64) ? o64 : o64 - 64;
#pragma unroll
      for (int reg = 0; reg < 4; ++reg) {
        float v0 = acc[i][0][reg] + bcv[reg];
        float v1 = acc[i][1][reg] + bcv[reg];
        float v2 = acc[i][2][reg] + bcv[reg];
        float v3 = acc[i][3][reg] + bcv[reg];
        float p0 = fmaxf(v0, v2);  // row pair (nt, nt^2)
        float p1 = fmaxf(v1, v3);
        p0 = fmaxf(p0, __shfl_xor(p0, 1, 64));  // col pair
        p1 = fmaxf(p1, __shfl_xor(p1, 1, 64));
        if ((lane16 & 1) == 0) {
          const int pc = lane16 >> 1;
          const size_t d = ((size_t)(n * 64) + oo + reg) * 1024 + rp * 32 + jh * 16;
          outp[d + pc] = p0;
          outp[d + 8 + pc] = p1;
        }
      }
    }
  }
}

// ---------------- 3. small ops: 3 pyramid pools + depth resizes
// pooled [3][n][64][85]; d1 [n][4096]; d2 [n][1024]
__global__ __launch_bounds__(256) void k_small(const float* __restrict__ t_in,
                                               const float* __restrict__ phi_in,
                                               const float* __restrict__ g_in,
                                               float* __restrict__ pooled,
                                               const float* __restrict__ depth,
                                               float* __restrict__ d1,
                                               float* __restrict__ d2) {
  __shared__ float red[64][4];
  __shared__ float s8[64];
  const int bid = blockIdx.x;
  const int t = threadIdx.x;
  if (bid < 768) {
    const int br = bid >> 8, blk = bid & 255;
    const int n = blk >> 6, c = blk & 63;
    const float* in = (br == 0) ? t_in : (br == 1) ? phi_in : g_in;
    const int H = (br == 0) ? 64 : 32;
    const int cell = t & 63, part = t >> 6;
    const int gy = cell >> 3, gx = cell & 7;
    const int k = H >> 3;
    const int rpp = (k >> 2) ? (k >> 2) : 1;
    const float* base = in + (size_t)(n * 64 + c) * H * H;
    float s = 0.f;
    for (int r = 0; r < rpp; ++r) {
      const int y = gy * k + part * rpp + r;
      const float* rpt = base + y * H + gx * k;
      for (int xx = 0; xx < k; xx += 4) {
        float4 v = *(const float4*)(rpt + xx);
        s += v.x + v.y + v.z + v.w;
      }
    }
    red[cell][part] = s;
    __syncthreads();
    if (t < 64) s8[t] = red[t][0] + red[t][1] + red[t][2] + red[t][3];
    __syncthreads();
    float* pout = pooled + ((size_t)(br * 4 + n) * 64 + c) * 85;
    const float inv = 1.f / (float)(k * k);
    if (t < 64) {
      pout[t] = s8[t] * inv;
    } else if (t < 80) {
      const int i2 = t - 64, gy2 = i2 >> 2, gx2 = i2 & 3;
      float v = s8[(2 * gy2) * 8 + 2 * gx2] + s8[(2 * gy2) * 8 + 2 * gx2 + 1] +
                s8[(2 * gy2 + 1) * 8 + 2 * gx2] + s8[(2 * gy2 + 1) * 8 + 2 * gx2 + 1];
      pout[64 + i2] = v * inv * 0.25f;
    } else if (t < 84) {
      const int i1 = t - 80, gy1 = i1 >> 1, gx1 = i1 & 1;
      float v = 0.f;
      for (int yy = 0; yy < 4; ++yy)
        for (int xx = 0; xx < 4; ++xx) v += s8[(gy1 * 4 + yy) * 8 + gx1 * 4 + xx];
      pout[80 + i1] = v * inv * 0.0625f;
    } else if (t == 84) {
      float v = 0.f;
      for (int i = 0; i < 64; ++i) v += s8[i];
      pout[84] = v * inv * (1.f / 64.f);
    }
  } else {
    const int blk2 = bid - 768;  // 0..79
    const int bx = blk2 >> 2, n = blk2 & 3;
    const float* dp = depth + (size_t)n * 65536;
    int i, j, idx;
    float scale;
    float* outp;
    if (bx < 16) {
      idx = bx * 256 + t;
      i = idx >> 6; j = idx & 63;
      scale = 255.f / 63.f;
      outp = d1 + (size_t)n * 4096;
    } else {
      idx = (bx - 16) * 256 + t;
      i = idx >> 5; j = idx & 31;
      scale = 255.f / 31.f;
      outp = d2 + (size_t)n * 1024;
    }
    const float sy = i * scale, sx = j * scale;
    const int ly = (int)sy, lx = (int)sx;
    const int hy = min(ly + 1, 255), hx = min(lx + 1, 255);
    const float fy = sy - ly, fx = sx - lx;
    const float v = (1.f - fy) * ((1.f - fx) * dp[ly * 256 + lx] + fx * dp[ly * 256 + hx]) +
                    fy * ((1.f - fx) * dp[hy * 256 + lx] + fx * dp[hy * 256 + hx]);
    outp[idx] = v;
  }
}

// ---------------- 4. pyramid fuse x3 (+ in-block poolconv)
// grid (96, n): bx<64 -> theta tile bx; 64..79 -> phi; 80..95 -> g
__global__ __launch_bounds__(256) void k_ppfuse3(
    const float* __restrict__ t_in, const float* __restrict__ phi_in,
    const float* __restrict__ g_in, const float* __restrict__ pooled,
    const float* __restrict__ tpw, const float* __restrict__ tga, const float* __restrict__ tbe,
    const float* __restrict__ tow, const float* __restrict__ tob,
    const float* __restrict__ ppw, const float* __restrict__ pga, const float* __restrict__ pbe,
    const float* __restrict__ pow_, const float* __restrict__ pob,
    const float* __restrict__ gpw, const float* __restrict__ gga, const float* __restrict__ gbe,
    const float* __restrict__ gow, const float* __restrict__ gob,
    ushort* __restrict__ thetaB, ushort* __restrict__ phiB, ushort* __restrict__ gB) {
  __shared__ __align__(16) float sh[9680];
  float* q_s = sh;                 // [85][16]
  float* bl = sh + 1360;           // [64][65]
  float* til = sh + 5520;          // [64][65]
  float* pooled_s = sh + 1360;     // [64][85] (dead before bl/til use)

  const int bx = blockIdx.x, n = blockIdx.y;
  const int t = threadIdx.x;
  int br, tile;
  if (bx < 64) { br = 0; tile = bx; }
  else if (bx < 80) { br = 1; tile = bx - 64; }
  else { br = 2; tile = bx - 80; }
  const int S = (br == 0) ? 64 : 32;
  const int lw = (br == 0) ? 6 : 5;
  const int pm = (br == 2) ? 0 : 1;
  const float* in = (br == 0) ? t_in : (br == 1) ? phi_in : g_in;
  const float* pw = (br == 0) ? tpw : (br == 1) ? ppw : gpw;
  const float* ga = (br == 0) ? tga : (br == 1) ? pga : gga;
  const float* be = (br == 0) ? tbe : (br == 1) ? pbe : gbe;
  const float* owp = (br == 0) ? tow : (br == 1) ? pow_ : gow;
  const float* obp = (br == 0) ? tob : (br == 1) ? pob : gob;
  ushort* out = (br == 0) ? thetaB : (br == 1) ? phiB : gB;
  const int P = S * S;
  const int pixbase = tile * 64;

  // phase A: stage pooled slice
  {
    const float* pb_ = pooled + ((size_t)(br * 4 + n) * 64) * 85;
    for (int i = t; i < 5440; i += 256) pooled_s[i] = pb_[i];
  }
  __syncthreads();
  // phase B: poolconv 64->16 + BN + ReLU -> q_s[85][16]
  {
    const float bnscale = 0.9999950000374997f;
    for (int idx = t; idx < 85 * 16; idx += 256) {
      const int pos = idx >> 4, o = idx & 15;
      const int s = (pos < 64) ? 0 : (pos < 80) ? 1 : (pos < 84) ? 2 : 3;
      const float* wp = pw + (s * 16 + o) * 64;
      float acc = 0.f;
      for (int c = 0; c < 64; ++c) acc += pooled_s[c * 85 + pos] * wp[c];
      acc = acc * bnscale * ga[s * 16 + o] + be[s * 16 + o];
      q_s[idx] = fmaxf(acc, 0.f);
    }
  }
  __syncthreads();

  const int p = t & 63, sc = t >> 6;
  // phase C1: bilinear blend of scale sc
  {
    const int pg = pixbase + p;
    const int y = pg >> lw, x = pg & (S - 1);
    const int ps = 8 >> sc;
    const int off = (sc == 0) ? 0 : (sc == 1) ? 64 : (sc == 2) ? 80 : 84;
    const float scale = (float)ps / (float)S;
    float syf = fminf(fmaxf((y + 0.5f) * scale - 0.5f, 0.f), (float)(ps - 1));
    float sxf = fminf(fmaxf((x + 0.5f) * scale - 0.5f, 0.f), (float)(ps - 1));
    const int ly = (int)syf, lx = (int)sxf;
    const int hy = min(ly + 1, ps - 1), hx = min(lx + 1, ps - 1);
    const float fy = syf - ly, fx = sxf - lx;
    const float w00 = (1.f - fy) * (1.f - fx), w01 = (1.f - fy) * fx;
    const float w10 = fy * (1.f - fx), w11 = fy * fx;
    const float4* r00 = (const float4*)(q_s + (off + ly * ps + lx) * 16);
    const float4* r01 = (const float4*)(q_s + (off + ly * ps + hx) * 16);
    const float4* r10 = (const float4*)(q_s + (off + hy * ps + lx) * 16);
    const float4* r11 = (const float4*)(q_s + (off + hy * ps + hx) * 16);
#pragma unroll
    for (int k = 0; k < 4; ++k) {
      float4 v00 = r00[k], v01 = r01[k], v10 = r10[k], v11 = r11[k];
      bl[p * 65 + sc * 16 + 4 * k + 0] = w00 * v00.x + w01 * v01.x + w10 * v10.x + w11 * v11.x;
      bl[p * 65 + sc * 16 + 4 * k + 1] = w00 * v00.y + w01 * v01.y + w10 * v10.y + w11 * v11.y;
      bl[p * 65 + sc * 16 + 4 * k + 2] = w00 * v00.z + w01 * v01.z + w10 * v10.z + w11 * v11.z;
      bl[p * 65 + sc * 16 + 4 * k + 3] = w00 * v00.w + w01 * v01.w + w10 * v10.w + w11 * v11.w;
    }
  }
  // phase C2: identity tile -> [pixel][c]
  {
    const float* ip = in + (size_t)n * 64 * P + pixbase + p;
#pragma unroll
    for (int k = 0; k < 16; ++k) {
      const int c = sc + 4 * k;
      til[p * 65 + c] = ip[(size_t)c * P];
    }
  }
  __syncthreads();
  // phase C3: 128->64 conv
  const int obase = sc * 16;
  float acc[16];
#pragma unroll
  for (int j = 0; j < 16; ++j) acc[j] = obp[obase + j];
  const float4* ow4 = (const float4*)owp;
#pragma unroll
  for (int c4 = 0; c4 < 16; ++c4) {
    const float4 tv = make_float4(til[p * 65 + 4 * c4], til[p * 65 + 4 * c4 + 1],
                                  til[p * 65 + 4 * c4 + 2], til[p * 65 + 4 * c4 + 3]);
    const float4 bv = make_float4(bl[p * 65 + 4 * c4], bl[p * 65 + 4 * c4 + 1],
                                  bl[p * 65 + 4 * c4 + 2], bl[p * 65 + 4 * c4 + 3]);
#pragma unroll
    for (int j = 0; j < 16; ++j) {
      const float4 wv = ow4[(obase + j) * 32 + c4];
      const float4 wb = ow4[(obase + j) * 32 + 16 + c4];
      acc[j] += tv.x * wv.x + tv.y * wv.y + tv.z * wv.z + tv.w * wv.w +
                bv.x * wb.x + bv.y * wb.y + bv.z * wb.z + bv.w * wb.w;
    }
  }
  // phase C4: store bf16
  if (pm) {
    __syncthreads();
#pragma unroll
    for (int j = 0; j < 16; ++j) til[p * 65 + obase + j] = acc[j];
    __syncthreads();
    const int p2 = t >> 2, c2 = (t & 3) * 16;
    uint pk[8];
#pragma unroll
    for (int i = 0; i < 8; ++i)
      pk[i] = (uint)f2bf(til[p2 * 65 + c2 + 2 * i]) | ((uint)f2bf(til[p2 * 65 + c2 + 2 * i + 1]) << 16);
    uint4* dst = (uint4*)(out + ((size_t)n * P + pixbase) * 64 + (size_t)t * 16);
    dst[0] = make_uint4(pk[0], pk[1], pk[2], pk[3]);
    dst[1] = make_uint4(pk[4], pk[5], pk[6], pk[7]);
  } else {
#pragma unroll
    for (int j = 0; j < 16; ++j)
      out[((size_t)n * 64 + obase + j) * P + pixbase + p] = f2bf(acc[j]);
  }
}

// ---------------- 5. attention (MFMA) + fused z-conv
// thetaB [n][4096][64], phiB [n][1024][64], gB [n][64][1024] (bf16);
// zw [128][64], zb [128] f32 -> z [n][128][4096] f32
__global__ __launch_bounds__(256) void k_attn(const ushort* __restrict__ thetaB,
                                              const ushort* __restrict__ phiB,
                                              const ushort* __restrict__ gB,
                                              const float* __restrict__ d1,
                                              const float* __restrict__ d2,
                                              const float* __restrict__ zw,
                                              const float* __restrict__ zb,
                                              float* __restrict__ z) {
  __shared__ __align__(16) char smem[4 * 16 * 264 * 2];  // s tile / ypart+ycomb
  __shared__ float redl[4][16][4];
  __shared__ float spv[16];
  ushort* sbuf = (ushort*)smem;
  float* ypart = (float*)smem;           // [4][16][68]
  float* ycomb = (float*)smem + 4352;    // [16][68]

  const int n = blockIdx.y, q0 = blockIdx.x * 16;
  const int t = threadIdx.x, w = t >> 6, l = t & 63;
  const int lane16 = l & 15, quad = l >> 4;
  const int v0 = w * 256;

  // GEMM1: a[16 x 256] = theta[16 x 64] * phi[64 x 256]
  f32x4 acc[16];
#pragma unroll
  for (int i = 0; i < 16; ++i) acc[i] = (f32x4){0.f, 0.f, 0.f, 0.f};
  const ushort* thA = thetaB + ((size_t)n * 4096 + q0 + lane16) * 64 + quad * 8;
  const ushort* phB = phiB + ((size_t)n * 1024 + v0 + lane16) * 64 + quad * 8;
#pragma unroll
  for (int ks = 0; ks < 2; ++ks) {
    bf16x8 av = *(const bf16x8*)(thA + ks * 32);
#pragma unroll
    for (int t16 = 0; t16 < 16; ++t16) {
      bf16x8 bv = *(const bf16x8*)(phB + t16 * 16 * 64 + ks * 32);
      acc[t16] = __builtin_amdgcn_mfma_f32_16x16x32_bf16(av, bv, acc[t16], 0, 0, 0);
    }
  }

  const float e6 = 1e-6f;
  float dq[4], iq[4];
  const float* d1p = d1 + (size_t)n * 4096 + q0 + quad * 4;
#pragma unroll
  for (int r = 0; r < 4; ++r) { dq[r] = d1p[r]; iq[r] = 1.f / (dq[r] + e6); }
  const float* d2p = d2 + (size_t)n * 1024 + v0 + lane16;

  float mx[4] = {-1e30f, -1e30f, -1e30f, -1e30f};
#pragma unroll
  for (int t16 = 0; t16 < 16; ++t16)
#pragma unroll
    for (int r = 0; r < 4; ++r) mx[r] = fmaxf(mx[r], acc[t16][r]);
#pragma unroll
  for (int r = 0; r < 4; ++r) mx[r] = red16max(mx[r]);
  if (lane16 == 0)
#pragma unroll
    for (int r = 0; r < 4; ++r) redl[w][quad * 4 + r][0] = mx[r];
  __syncthreads();
  float m[4];
#pragma unroll
  for (int r = 0; r < 4; ++r) {
    float v = redl[0][quad * 4 + r][0];
    v = fmaxf(v, redl[1][quad * 4 + r][0]);
    v = fmaxf(v, redl[2][quad * 4 + r][0]);
    m[r] = fmaxf(v, redl[3][quad * 4 + r][0]);
  }

  float se[4] = {0.f, 0.f, 0.f, 0.f}, sr[4] = {0.f, 0.f, 0.f, 0.f};
#pragma unroll
  for (int t16 = 0; t16 < 16; ++t16) {
    const float dd = d2p[t16 * 16];
    const float idd = 1.f / (dd + e6);
#pragma unroll
    for (int r = 0; r < 4; ++r) {
      const float rv = fminf(dq[r] * idd, dd * iq[r]);
      const float er = __expf(rv);
      const float ea = __expf(acc[t16][r] - m[r]);
      acc[t16][r] = ea * er;
      se[r] += ea; sr[r] += er;
    }
  }
#pragma unroll
  for (int r = 0; r < 4; ++r) { se[r] = red16sum(se[r]); sr[r] = red16sum(sr[r]); }
  if (lane16 == 0)
#pragma unroll
    for (int r = 0; r < 4; ++r) {
      redl[w][quad * 4 + r][1] = se[r];
      redl[w][quad * 4 + r][2] = sr[r];
    }
  __syncthreads();
  float U[4];
#pragma unroll
  for (int r = 0; r < 4; ++r) {
    const int row = quad * 4 + r;
    const float set = redl[0][row][1] + redl[1][row][1] + redl[2][row][1] + redl[3][row][1];
    const float srt = redl[0][row][2] + redl[1][row][2] + redl[2][row][2] + redl[3][row][2];
    U[r] = 1.f / (set * srt);
  }

  float sp[4] = {0.f, 0.f, 0.f, 0.f};
#pragma unroll
  for (int t16 = 0; t16 < 16; ++t16)
#pragma unroll
    for (int r = 0; r < 4; ++r) {
      const float s_ = __expf(U[r] * acc[t16][r]);
      acc[t16][r] = s_;
      sp[r] += s_;
    }
#pragma unroll
  for (int r = 0; r < 4; ++r) sp[r] = red16sum(sp[r]);
  if (lane16 == 0)
#pragma unroll
    for (int r = 0; r < 4; ++r) redl[w][quad * 4 + r][3] = sp[r];
  __syncthreads();
  if (w == 0 && lane16 == 0)
#pragma unroll
    for (int r = 0; r < 4; ++r) {
      const int row = quad * 4 + r;
      spv[row] = 1.f / (redl[0][row][3] + redl[1][row][3] + redl[2][row][3] + redl[3][row][3]);
    }

  ushort* srow = sbuf + w * (16 * 264);
#pragma unroll
  for (int t16 = 0; t16 < 16; ++t16)
#pragma unroll
    for (int r = 0; r < 4; ++r)
      srow[(quad * 4 + r) * 264 + t16 * 16 + lane16] = f2bf(acc[t16][r]);
  __syncthreads();

  // GEMM2: y_partial[16 x 64] = s[16 x 256] * g[256 x 64]
  f32x4 acc2[4];
#pragma unroll
  for (int i = 0; i < 4; ++i) acc2[i] = (f32x4){0.f, 0.f, 0.f, 0.f};
  const ushort* sA = sbuf + w * (16 * 264) + lane16 * 264 + quad * 8;
  const ushort* gq = gB + (size_t)n * 65536 + v0 + quad * 8;
#pragma unroll
  for (int kk = 0; kk < 8; ++kk) {
    bf16x8 av = *(const bf16x8*)(sA + kk * 32);
#pragma unroll
    for (int tn = 0; tn < 4; ++tn) {
      bf16x8 bv = *(const bf16x8*)(gq + (size_t)(tn * 16 + lane16) * 1024 + kk * 32);
      acc2[tn] = __builtin_amdgcn_mfma_f32_16x16x32_bf16(av, bv, acc2[tn], 0, 0, 0);
    }
  }
  __syncthreads();  // s reads done; ypart aliases sbuf
  float* yp = ypart + w * (16 * 68);
#pragma unroll
  for (int tn = 0; tn < 4; ++tn)
#pragma unroll
    for (int r = 0; r < 4; ++r)
      yp[(quad * 4 + r) * 68 + tn * 16 + lane16] = acc2[tn][r];
  __syncthreads();
  // cross-wave K-combine + 1/sp -> ycomb
  {
    const int row = t >> 4, c0 = (t & 15) * 4;
    float4 s0 = *(const float4*)(ypart + 0 * 1088 + row * 68 + c0);
    float4 s1 = *(const float4*)(ypart + 1 * 1088 + row * 68 + c0);
    float4 s2 = *(const float4*)(ypart + 2 * 1088 + row * 68 + c0);
    float4 s3 = *(const float4*)(ypart + 3 * 1088 + row * 68 + c0);
    const float isp = spv[row];
    float4 o;
    o.x = (s0.x + s1.x + s2.x + s3.x) * isp;
    o.y = (s0.y + s1.y + s2.y + s3.y) * isp;
    o.z = (s0.z + s1.z + s2.z + s3.z) * isp;
    o.w = (s0.w + s1.w + s2.w + s3.w) * isp;
    *(float4*)(ycomb + row * 68 + c0) = o;
  }
  __syncthreads();
  // fused z-conv: z[128 out][16 px] = zw[128][64] * ycomb[16 px][64]
  {
    const int px = t & 15, og = t >> 4;  // og: 16 groups x 8 outputs
    float a8[8];
#pragma unroll
    for (int j = 0; j < 8; ++j) a8[j] = zb[og * 8 + j];
    const float4* zw4 = (const float4*)zw;
#pragma unroll
    for (int c4 = 0; c4 < 16; ++c4) {
      const float4 yv = *(const float4*)(ycomb + px * 68 + c4 * 4);
#pragma unroll
      for (int j = 0; j < 8; ++j) {
        const float4 wv = zw4[(og * 8 + j) * 16 + c4];
        a8[j] += yv.x * wv.x + yv.y * wv.y + yv.z * wv.z + yv.w * wv.w;
      }
    }
    const size_t zb0 = ((size_t)n * 128 + og * 8) * 4096 + q0 + px;
#pragma unroll
    for (int j = 0; j < 8; ++j) z[zb0 + (size_t)j * 4096] = a8[j];
  }
}

// ---------------- 6. final: out = x + bilinear_up(z, 64->256, align=True)
__global__ __launch_bounds__(256) void k_final(const float* __restrict__ x,
                                               const float* __restrict__ z,
                                               float* __restrict__ out) {
  const int n = blockIdx.z, c = blockIdx.y;
  const int Y = blockIdx.x * 4 + (threadIdx.x >> 6);
  const int X0 = (threadIdx.x & 63) * 4;
  const float s = 63.f / 255.f;
  const float sy = Y * s;
  const int ly = (int)sy;
  const int hy = min(ly + 1, 63);
  const float fy = sy - ly;
  const float* zp = z + (size_t)(n * 128 + c) * 4096;
  float4 o;
  float* po = &o.x;
#pragma unroll
  for (int k = 0; k < 4; ++k) {
    const float sx = (X0 + k) * s;
    const int lx = (int)sx;
    const int hx = min(lx + 1, 63);
    const float fx = sx - lx;
    po[k] = (1.f - fy) * ((1.f - fx) * zp[ly * 64 + lx] + fx * zp[ly * 64 + hx]) +
            fy * ((1.f - fx) * zp[hy * 64 + lx] + fx * zp[hy * 64 + hx]);
  }
  const size_t idx = ((size_t)(n * 128 + c) * 256 + Y) * 256 + X0;
  const float4 xv = *(const float4*)(x + idx);
  o.x += xv.x; o.y += xv.y; o.z += xv.z; o.w += xv.w;
  *(float4*)(out + idx) = o;
}

// ---------------------------------------------------------------- launcher
extern "C" void kernel_launch(void* const* d_in, const int* in_sizes, int n_in,
                              void* d_out, int out_size, void* d_ws, size_t ws_size,
                              hipStream_t stream) {
  const float* x       = (const float*)d_in[0];
  const float* depth   = (const float*)d_in[1];
  const float* down_w  = (const float*)d_in[2];
  const float* theta_w = (const float*)d_in[3];
  const float* theta_b = (const float*)d_in[4];
  const float* phi_w   = (const float*)d_in[5];
  const float* phi_b   = (const float*)d_in[6];
  const float* g_w     = (const float*)d_in[7];
  const float* g_b     = (const float*)d_in[8];
  const float* z_w     = (const float*)d_in[9];
  const float* z_b     = (const float*)d_in[10];
  const float* ppg_pw    = (const float*)d_in[11];
  const float* ppg_gamma = (const float*)d_in[12];
  const float* ppg_beta  = (const float*)d_in[13];
  const float* ppg_ow    = (const float*)d_in[14];
  const float* ppg_ob    = (const float*)d_in[15];
  const float* ppt_pw    = (const float*)d_in[16];
  const float* ppt_gamma = (const float*)d_in[17];
  const float* ppt_beta  = (const float*)d_in[18];
  const float* ppt_ow    = (const float*)d_in[19];
  const float* ppt_ob    = (const float*)d_in[20];
  const float* ppp_pw    = (const float*)d_in[21];
  const float* ppp_gamma = (const float*)d_in[22];
  const float* ppp_beta  = (const float*)d_in[23];
  const float* ppp_ow    = (const float*)d_in[24];
  const float* ppp_ob    = (const float*)d_in[25];

  float* ws = (float*)d_ws;
  float* xd      = ws;                        // [4][128][4096]; z aliases after cfuse
  float* zbuf    = ws;
  float* t_in    = ws + 2097152;              // [4][64][4096]
  float* phi_in  = ws + 3145728;              // [4][64][1024]
  float* g_in    = ws + 3407872;              // [4][64][1024]
  float* pooled  = ws + 3670016;              // [3][4][64][85]
  float* d1      = ws + 3735296;              // [4][4096]
  float* d2      = ws + 3751680;              // [4][1024]
  ushort* thetaB = (ushort*)(ws + 3755776);   // [4][4096][64] bf16
  ushort* phiB   = (ushort*)(ws + 4280064);   // [4][1024][64] bf16
  ushort* gB     = (ushort*)(ws + 4411136);   // [4][64][1024] bf16
  ushort* Wb     = (ushort*)(ws + 4542208);   // [192][128] bf16
  float* Bc      = ws + 4554496;              // [192]
  // total 4554688 floats = 17.4 MiB

  dim3 b(256);
  k_down<<<dim3(8193), b, 0, stream>>>(x, down_w, xd, theta_w, theta_b, phi_w, phi_b,
                                       g_w, g_b, Wb, Bc);
  k_cfuse<<<dim3(256), b, 0, stream>>>(xd, Wb, Bc, t_in, phi_in, g_in);
  k_small<<<dim3(848), b, 0, stream>>>(t_in, phi_in, g_in, pooled, depth, d1, d2);
  k_ppfuse3<<<dim3(96, 4), b, 0, stream>>>(t_in, phi_in, g_in, pooled,
                                           ppt_pw, ppt_gamma, ppt_beta, ppt_ow, ppt_ob,
                                           ppp_pw, ppp_gamma, ppp_beta, ppp_ow, ppp_ob,
                                           ppg_pw, ppg_gamma, ppg_beta, ppg_ow, ppg_ob,
                                           thetaB, phiB, gB);
  k_attn<<<dim3(256, 4), b, 0, stream>>>(thetaB, phiB, gB, d1, d2, z_w, z_b, zbuf);
  k_final<<<dim3(64, 128, 4), b, 0, stream>>>(x, zbuf, (float*)d_out);
}